// Round 1
// baseline (260.995 us; speedup 1.0000x reference)
//
#include <hip/hip_runtime.h>
#include <hip/hip_bf16.h>
#include <stdint.h>

#define N_REP 8
#define BATCH 32
#define NIN   128
#define NOUT  128
#define EDIM  1024
#define MDIM  130
#define ETILE 64
#define NGRP  32    // 128 m-rows / 4 rows per group
#define GSTR  260   // dwords per 4-row group: 256 data + 4 pad; q-step = 2 groups = 520 dw = +8 banks (2-way free)

typedef __attribute__((ext_vector_type(8))) short short8;
typedef __attribute__((ext_vector_type(4))) float f32x4;

__device__ __forceinline__ unsigned short f2bf(float f) {
    union { float f; uint32_t u; } v;
    v.f = f;
    uint32_t u = v.u;
    uint32_t r = u + 0x7fffu + ((u >> 16) & 1u);   // RNE
    return (unsigned short)(r >> 16);
}

__device__ __forceinline__ uint32_t pk2bf(float lo, float hi) {
    __hip_bfloat162 h = __float22bfloat162_rn(make_float2(lo, hi)); // .x -> low16
    uint32_t d;
    __builtin_memcpy(&d, &h, 4);
    return d;
}

__device__ __forceinline__ void gload_lds16(float* lds, const float* g) {
    __builtin_amdgcn_global_load_lds(
        (const __attribute__((address_space(1))) void*)g,
        (__attribute__((address_space(3))) void*)lds, 16, 0, 0);
}

// One wave per (n,o). m parallel across lanes: m = lane, lane+64, (lane<2: 128+lane).
// Emits S[n][o][m] = W*sign (bf16, K-minor) and bias[n][o] = sum Wneg(m<128) + Wpos(m=128).
__global__ __launch_bounds__(64)
void prep_kernel(const float* __restrict__ theta,
                 const float* __restrict__ noise,
                 unsigned short* __restrict__ Sg,
                 float* __restrict__ biasg) {
    const int n = blockIdx.x >> 7;
    const int o = blockIdx.x & 127;
    const int lane = threadIdx.x;

    const float* nb = noise + (size_t)n * MDIM * NOUT + o;
    auto tn_at = [&](int m) -> float {
        float t = theta[m * NOUT + o];
        t = fminf(fmaxf(t, -1.f), 1.f);
        if (fabsf(t) < 0.01f) t = 0.f;
        return t * fmaf(nb[m * NOUT], 0.2f, 0.9f);
    };

    const float t0 = tn_at(lane);
    const float t1 = tn_at(lane + 64);
    const float t2 = (lane < 2) ? tn_at(128 + lane) : 0.f;

    float s = fabsf(t0) + fabsf(t1) + fabsf(t2);
#pragma unroll
    for (int d = 1; d < 64; d <<= 1) s += __shfl_xor(s, d, 64);
    const float inv = 1.f / (s + 1e-10f);

    const float w0 = fabsf(t0) * inv, w1 = fabsf(t1) * inv;
    unsigned short* srow = Sg + ((size_t)n * NOUT + o) * NIN;
    srow[lane]      = f2bf(t0 >= 0.f ? w0 : -w0);
    srow[lane + 64] = f2bf(t1 >= 0.f ? w1 : -w1);

    float b = (t0 < 0.f ? w0 : 0.f) + (t1 < 0.f ? w1 : 0.f);
    if (lane == 0 && t2 >= 0.f) b += fabsf(t2) * inv;   // ones-column positive part
#pragma unroll
    for (int d = 1; d < 64; d <<= 1) b += __shfl_xor(b, d, 64);
    if (lane == 0) biasg[n * NOUT + o] = b;
}

// out[nb][o][e] = tanh-act( sum_m a[nb][m][e] * S[n][o][m] + bias[n][o] ).
// Stage raw fp32 a-tile [m=128][e=64] into LDS via async global_load_lds (wave-uniform
// base + lane*16 => 4 rows of 64 floats per instr, one 4-row group per instr).
// LDS: 32 groups * (256 data + 4 pad) dwords = 33280 B -> 4 blocks/CU.
// Fragment build converts fp32->bf16 (pk pairs). MFMA: A = a (rows=e), B = S (cols=o),
// so each lane owns 4 consecutive e -> float4 epilogue stores.
__global__ __launch_bounds__(256, 4)
void gemm_kernel(const float* __restrict__ a,
                 const unsigned short* __restrict__ Sg,
                 const float* __restrict__ biasg,
                 const float* __restrict__ eta,
                 float* __restrict__ out) {
    __shared__ float Alds[NGRP * GSTR];              // 33280 B
    const int bid  = blockIdx.x;
    const int et   = bid & 15;                       // e-tile (64 wide)
    const int nb   = bid >> 4;                       // n*B + b
    const int n    = nb >> 5;
    const int tid  = threadIdx.x;
    const int lane = tid & 63;
    const int w    = tid >> 6;                       // 4 waves: 2(o) x 2(e)
    const int r    = lane & 15;
    const int q    = lane >> 4;

    // ---- async stage: 8 group-loads per wave, issued back-to-back ----
    {
        const float* gp = a + (size_t)nb * (NIN * EDIM)
                            + (size_t)(w * 32 + q) * EDIM + et * ETILE + (r << 2);
        float* lp = &Alds[(w * 8) * GSTR];
#pragma unroll
        for (int t = 0; t < 8; ++t)
            gload_lds16(lp + t * GSTR, gp + (size_t)(t * 4) * EDIM);
    }

    const int o_base = (w & 1) << 6;
    const int e_base = (w >> 1) << 5;

    // uniform + L2-hot loads issued while the DMA streams
    const float e0 = eta[0], e1 = eta[1], e2 = eta[2], e3 = eta[3];
    float bl[4];
#pragma unroll
    for (int fo = 0; fo < 4; ++fo)
        bl[fo] = biasg[n * NOUT + o_base + (fo << 4) + r];

    const unsigned short* sbase = Sg + ((size_t)(n * NOUT) << 7) + (q << 3);
    short8 sf[4];
#pragma unroll
    for (int fo = 0; fo < 4; ++fo)
        sf[fo] = *(const short8*)(sbase + ((size_t)(o_base + (fo << 4) + r) << 7));

    f32x4 acc[4][2];
#pragma unroll
    for (int fo = 0; fo < 4; ++fo)
#pragma unroll
        for (int fe = 0; fe < 2; ++fe)
            acc[fo][fe] = (f32x4){0.f, 0.f, 0.f, 0.f};

    __syncthreads();                                 // drains vmcnt(0): DMA complete

#pragma unroll
    for (int ks = 0; ks < 4; ++ks) {
        short8 sfn[4];
        if (ks < 3) {
#pragma unroll
            for (int fo = 0; fo < 4; ++fo)
                sfn[fo] = *(const short8*)(sbase + ((size_t)(o_base + (fo << 4) + r) << 7)
                                                 + ((ks + 1) << 5));
        }
        // a fragments: 8 fp32 at m = ks*32 + q*8 + j, e = e_base + fe*16 + r
        // lane banks: (8q + r) mod 32 -> exact 2-way aliasing (free)
        short8 af[2];
#pragma unroll
        for (int fe = 0; fe < 2; ++fe) {
            const float* base = &Alds[(ks * 8 + q * 2) * GSTR + e_base + (fe << 4) + r];
            uint32_t d[4];
#pragma unroll
            for (int t = 0; t < 4; ++t) {
                const int j0 = 2 * t, j1 = 2 * t + 1;
                const float f0 = base[(j0 >> 2) * GSTR + (j0 & 3) * 64];
                const float f1 = base[(j1 >> 2) * GSTR + (j1 & 3) * 64];
                d[t] = pk2bf(f0, f1);
            }
            __builtin_memcpy(&af[fe], d, 16);
        }
#pragma unroll
        for (int fo = 0; fo < 4; ++fo)
#pragma unroll
            for (int fe = 0; fe < 2; ++fe)
                acc[fo][fe] = __builtin_amdgcn_mfma_f32_16x16x32_bf16(
                    af[fe], sf[fo], acc[fo][fe], 0, 0, 0);
        if (ks < 3) {
#pragma unroll
            for (int fo = 0; fo < 4; ++fo)
                sf[fo] = sfn[fo];
        }
    }

    // ---- epilogue: bias + printed tanh; lane owns e = .. + q*4 + {0..3} -> float4 ----
    float* obase = out + (size_t)nb * (NOUT * EDIM) + et * ETILE;
#pragma unroll
    for (int fo = 0; fo < 4; ++fo) {
        float* orow = obase + (size_t)(o_base + (fo << 4) + r) * EDIM;
        const float bv = bl[fo];
#pragma unroll
        for (int fe = 0; fe < 2; ++fe) {
            f32x4 res;
#pragma unroll
            for (int i = 0; i < 4; ++i) {
                const float z = acc[fo][fe][i] + bv;
                const float y = (z - e2) * e3;
                const float ex = __expf(2.f * y);
                const float th = 1.f - 2.f * __builtin_amdgcn_rcpf(ex + 1.f);
                res[i] = fmaf(e1, th, e0);
            }
            *(f32x4*)(orow + e_base + (fe << 4) + (q << 2)) = res;
        }
    }
}

extern "C" void kernel_launch(void* const* d_in, const int* in_sizes, int n_in,
                              void* d_out, int out_size, void* d_ws, size_t ws_size,
                              hipStream_t stream) {
    const float* a     = (const float*)d_in[0];
    const float* theta = (const float*)d_in[1];
    const float* noise = (const float*)d_in[2];
    const float* eta   = (const float*)d_in[3];
    float* out = (float*)d_out;

    unsigned short* Sg = (unsigned short*)d_ws;      // 8*128*128 bf16 = 256 KiB
    float* biasg = (float*)((char*)d_ws + (size_t)N_REP * NOUT * NIN * sizeof(unsigned short));

    prep_kernel<<<N_REP * NOUT, 64, 0, stream>>>(theta, noise, Sg, biasg);
    gemm_kernel<<<N_REP * BATCH * (EDIM / ETILE), 256, 0, stream>>>(a, Sg, biasg, eta, out);
}

// Round 3
// 253.975 us; speedup vs baseline: 1.0276x; 1.0276x over previous
//
#include <hip/hip_runtime.h>
#include <hip/hip_bf16.h>
#include <stdint.h>

#define N_REP 8
#define BATCH 32
#define NIN   128
#define NOUT  128
#define EDIM  1024
#define MDIM  130
#define ETILE 64
#define NT    4     // e-tiles per block, double-buffered pipeline
#define NGRP  32    // 128 m-rows / 4 rows per group
#define GSTR  260   // dwords per 4-row group: 256 data + 4 pad; q-step = 520 dw => 2-way (free)

typedef __attribute__((ext_vector_type(8))) short short8;
typedef __attribute__((ext_vector_type(4))) float f32x4;

__device__ __forceinline__ unsigned short f2bf(float f) {
    union { float f; uint32_t u; } v;
    v.f = f;
    uint32_t u = v.u;
    uint32_t r = u + 0x7fffu + ((u >> 16) & 1u);   // RNE
    return (unsigned short)(r >> 16);
}

__device__ __forceinline__ uint32_t pk2bf(float lo, float hi) {
    __hip_bfloat162 h = __float22bfloat162_rn(make_float2(lo, hi)); // .x -> low16
    uint32_t d;
    __builtin_memcpy(&d, &h, 4);
    return d;
}

__device__ __forceinline__ void gload_lds16(float* lds, const float* g) {
    __builtin_amdgcn_global_load_lds(
        (const __attribute__((address_space(1))) void*)g,
        (__attribute__((address_space(3))) void*)lds, 16, 0, 0);
}

// One wave per (n,o). m parallel across lanes: m = lane, lane+64, (lane<2: 128+lane).
// Emits S[n][o][m] = W*sign (bf16, K-minor) and bias[n][o] = sum Wneg(m<128) + Wpos(m=128).
__global__ __launch_bounds__(64)
void prep_kernel(const float* __restrict__ theta,
                 const float* __restrict__ noise,
                 unsigned short* __restrict__ Sg,
                 float* __restrict__ biasg) {
    const int n = blockIdx.x >> 7;
    const int o = blockIdx.x & 127;
    const int lane = threadIdx.x;

    const float* nb = noise + (size_t)n * MDIM * NOUT + o;
    auto tn_at = [&](int m) -> float {
        float t = theta[m * NOUT + o];
        t = fminf(fmaxf(t, -1.f), 1.f);
        if (fabsf(t) < 0.01f) t = 0.f;
        return t * fmaf(nb[m * NOUT], 0.2f, 0.9f);
    };

    const float t0 = tn_at(lane);
    const float t1 = tn_at(lane + 64);
    const float t2 = (lane < 2) ? tn_at(128 + lane) : 0.f;

    float s = fabsf(t0) + fabsf(t1) + fabsf(t2);
#pragma unroll
    for (int d = 1; d < 64; d <<= 1) s += __shfl_xor(s, d, 64);
    const float inv = 1.f / (s + 1e-10f);

    const float w0 = fabsf(t0) * inv, w1 = fabsf(t1) * inv;
    unsigned short* srow = Sg + ((size_t)n * NOUT + o) * NIN;
    srow[lane]      = f2bf(t0 >= 0.f ? w0 : -w0);
    srow[lane + 64] = f2bf(t1 >= 0.f ? w1 : -w1);

    float b = (t0 < 0.f ? w0 : 0.f) + (t1 < 0.f ? w1 : 0.f);
    if (lane == 0 && t2 >= 0.f) b += fabsf(t2) * inv;   // ones-column positive part
#pragma unroll
    for (int d = 1; d < 64; d <<= 1) b += __shfl_xor(b, d, 64);
    if (lane == 0) biasg[n * NOUT + o] = b;
}

// out[nb][o][e] = tanh-act( sum_m a[nb][m][e] * S[n][o][m] + bias[n][o] ).
// Pipelined: each block owns 4 consecutive e-tiles of 64; while computing tile t it
// DMA-stages tile t+1 into the other LDS buffer (global_load_lds, zero VALU).
// Raw s_barrier + counted s_waitcnt vmcnt(8) so the prefetch is never drained
// (stores ride; only the 8 stage loads must land). S-frags + bias hoisted (reused x4).
__global__ __launch_bounds__(256, 2)
void gemm_kernel(const float* __restrict__ a,
                 const unsigned short* __restrict__ Sg,
                 const float* __restrict__ biasg,
                 const float* __restrict__ eta,
                 float* __restrict__ out) {
    __shared__ float Alds[2][NGRP * GSTR];           // 2 x 33280 B = 66560 B -> 2 blocks/CU
    const int bid  = blockIdx.x;
    const int nb   = bid >> 2;                       // n*B + b
    const int n    = nb >> 5;
    const int et0  = (bid & 3) << 2;                 // first of 4 consecutive e-tiles
    const int tid  = threadIdx.x;
    const int lane = tid & 63;
    const int w    = tid >> 6;                       // 4 waves: 2(o) x 2(e)
    const int r    = lane & 15;
    const int q    = lane >> 4;

    const float* gbase = a + (size_t)nb * (NIN * EDIM)
                           + (size_t)(w * 32 + q) * EDIM + et0 * ETILE + (r << 2);

    auto stage = [&](int buf, int t) {               // 8 async DMA per wave = 32 KB/block
        const float* gp = gbase + t * ETILE;
        float* lp = &Alds[buf][(w * 8) * GSTR];
#pragma unroll
        for (int k = 0; k < 8; ++k)
            gload_lds16(lp + k * GSTR, gp + (size_t)(k * 4) * EDIM);
    };

    stage(0, 0);                                     // tile 0 in flight immediately

    const int o_base = (w & 1) << 6;
    const int e_base = (w >> 1) << 5;

    // hoisted: eta, bias, and ALL S fragments (L2-hot, reused across the 4 e-tiles)
    // eta scalars forced into VGPRs: avoids two-SGPR VOP3 (constant-bus violation)
    float e0 = eta[0], e1 = eta[1], e2 = eta[2], e3 = eta[3];
    asm volatile("" : "+v"(e0), "+v"(e1), "+v"(e2), "+v"(e3));
    float bl[4];
#pragma unroll
    for (int fo = 0; fo < 4; ++fo)
        bl[fo] = biasg[n * NOUT + o_base + (fo << 4) + r];

    const unsigned short* sbase = Sg + ((size_t)(n * NOUT) << 7) + (q << 3);
    short8 sfr[4][4];                                // [ks][fo]
#pragma unroll
    for (int ks = 0; ks < 4; ++ks)
#pragma unroll
        for (int fo = 0; fo < 4; ++fo)
            sfr[ks][fo] = *(const short8*)(sbase + ((size_t)(o_base + (fo << 4) + r) << 7)
                                                 + (ks << 5));

    __syncthreads();                                 // prologue: full drain, tile 0 ready

    float* obase0 = out + (size_t)nb * (NOUT * EDIM) + et0 * ETILE;

#pragma unroll
    for (int t = 0; t < NT; ++t) {
        const int cur = t & 1;
        if (t + 1 < NT) stage(cur ^ 1, t + 1);       // prefetch next tile
        __builtin_amdgcn_sched_barrier(0);           // pin: all stage issued before compute

        f32x4 acc[4][2];
#pragma unroll
        for (int fo = 0; fo < 4; ++fo)
#pragma unroll
            for (int fe = 0; fe < 2; ++fe)
                acc[fo][fe] = (f32x4){0.f, 0.f, 0.f, 0.f};

#pragma unroll
        for (int ks = 0; ks < 4; ++ks) {
            // a fragments: 8 fp32 at m = ks*32 + q*8 + j, e = e_base + fe*16 + r
            // lane banks: (8q + r) mod 32 -> exact 2-way aliasing (free)
            short8 af[2];
#pragma unroll
            for (int fe = 0; fe < 2; ++fe) {
                const float* base = &Alds[cur][(ks * 8 + q * 2) * GSTR + e_base + (fe << 4) + r];
                uint32_t d[4];
#pragma unroll
                for (int tt = 0; tt < 4; ++tt) {
                    const int j0 = 2 * tt, j1 = 2 * tt + 1;
                    const float f0 = base[(j0 >> 2) * GSTR + (j0 & 3) * 64];
                    const float f1 = base[(j1 >> 2) * GSTR + (j1 & 3) * 64];
                    d[tt] = pk2bf(f0, f1);
                }
                __builtin_memcpy(&af[fe], d, 16);
            }
#pragma unroll
            for (int fo = 0; fo < 4; ++fo)
#pragma unroll
                for (int fe = 0; fe < 2; ++fe)
                    acc[fo][fe] = __builtin_amdgcn_mfma_f32_16x16x32_bf16(
                        af[fe], sfr[ks][fo], acc[fo][fe], 0, 0, 0);
        }

        // epilogue tile t: bias + printed tanh; lane owns 4 consecutive e -> float4
        float* obase = obase0 + t * ETILE;
#pragma unroll
        for (int fo = 0; fo < 4; ++fo) {
            float* orow = obase + (size_t)(o_base + (fo << 4) + r) * EDIM;
            const float bv = bl[fo];
#pragma unroll
            for (int fe = 0; fe < 2; ++fe) {
                f32x4 res;
#pragma unroll
                for (int i = 0; i < 4; ++i) {
                    const float z = acc[fo][fe][i] + bv;
                    const float y = (z - e2) * e3;
                    const float ex = __expf(2.f * y);
                    const float th = 1.f - 2.f * __builtin_amdgcn_rcpf(ex + 1.f);
                    res[i] = fmaf(e1, th, e0);
                }
                *(f32x4*)(orow + e_base + (fe << 4) + (q << 2)) = res;
            }
        }

        if (t + 1 < NT) {
            __builtin_amdgcn_sched_barrier(0);       // pin: stores issued before the wait
            // per-wave vmem order this iter: [8 stage][8 stores]; vmcnt(8) => stage
            // complete, stores may still be outstanding (never drain to 0 in-loop)
            asm volatile("s_waitcnt vmcnt(8)" ::: "memory");
            __builtin_amdgcn_s_barrier();
            __builtin_amdgcn_sched_barrier(0);       // pin: no ds_read hoisted above barrier
        }
    }
}

extern "C" void kernel_launch(void* const* d_in, const int* in_sizes, int n_in,
                              void* d_out, int out_size, void* d_ws, size_t ws_size,
                              hipStream_t stream) {
    const float* a     = (const float*)d_in[0];
    const float* theta = (const float*)d_in[1];
    const float* noise = (const float*)d_in[2];
    const float* eta   = (const float*)d_in[3];
    float* out = (float*)d_out;

    unsigned short* Sg = (unsigned short*)d_ws;      // 8*128*128 bf16 = 256 KiB
    float* biasg = (float*)((char*)d_ws + (size_t)N_REP * NOUT * NIN * sizeof(unsigned short));

    prep_kernel<<<N_REP * NOUT, 64, 0, stream>>>(theta, noise, Sg, biasg);
    gemm_kernel<<<N_REP * BATCH * (EDIM / ETILE / NT), 256, 0, stream>>>(a, Sg, biasg, eta, out);
}